// Round 12
// baseline (18108.022 us; speedup 1.0000x reference)
//
#include <hip/hip_runtime.h>

typedef unsigned short u16;
typedef unsigned int   u32;
typedef _Float16 v8hf __attribute__((ext_vector_type(8)));
typedef float  f32x4 __attribute__((ext_vector_type(4)));
typedef u32    u32x2 __attribute__((ext_vector_type(2)));

// ---------------- problem constants ----------------
static constexpr int B_   = 2048;
static constexpr int T_   = 64;
static constexpr int D_   = 64;
static constexpr int H_   = 256;
static constexpr int NL_  = 10;
static constexpr int FUT_ = 96;
static constexpr int NBLK = 128;     // B/16

// ---- workspace layout (bytes), proven <= 90 MiB ----
static constexpr size_t WFH_OFF  = 0;                     // Whh frags: 10 x 512 KiB
static constexpr size_t WFX_OFF  = 5u << 20;              // Wih frags: 10 x 512 KiB slots
static constexpr size_t XG_OFF   = 10u << 20;             // xg ring: 128 blk x 128 KiB = 16 MiB
static constexpr size_t SEQ2_OFF = 26u << 20;             // seq: 64 MiB
static constexpr int    WFL9 = 262144;                    // u16 per layer frag slot
static constexpr int    TCH  = 4;                         // timesteps per chunk

// ---------------- small helpers ----------------
__device__ __forceinline__ u16 f2h(float f) {
  _Float16 h = (_Float16)f;
  return __builtin_bit_cast(u16, h);
}
__device__ __forceinline__ float h2f(u16 b) {
  return (float)__builtin_bit_cast(_Float16, b);
}
__device__ __forceinline__ float rcp_(float x) { return __builtin_amdgcn_rcpf(x); }
__device__ __forceinline__ float fsig(float x) { return rcp_(1.f + __expf(-x)); }
__device__ __forceinline__ float ftanh(float x) {
  float e = __expf(-2.f * fabsf(x));
  float t = (1.f - e) * rcp_(1.f + e);
  return copysignf(t, x);
}
__device__ __forceinline__ void gld16(const u16* g, u16* l) {
  __builtin_amdgcn_global_load_lds(
      (const __attribute__((address_space(1))) void*)g,
      (__attribute__((address_space(3))) void*)l,
      16, 0, 0);
}

// ---------------- weight packing (fp16 B-fragment order, [kc][cg][gate]) ----------------
// frag(kc,cg,g)[lane][i] = W[g*256+cg*16+(lane&15)][kc*32+(lane>>4)*8+i]
__global__ void pack_weights_v11(const float* __restrict__ Wih0,
                                 const float* __restrict__ Wih,
                                 const float* __restrict__ Whh,
                                 u16* __restrict__ wfh,
                                 u16* __restrict__ wfx) {
  int gid = blockIdx.x * 256 + threadIdx.x;
  int lw  = gid >> 15;                   // l*2 + which
  if (lw >= NL_ * 2) return;
  int l = lw >> 1, which = lw & 1;
  int rem  = gid & 32767;
  int kc   = rem >> 12;                  // 0..7
  int cg   = (rem >> 8) & 15;
  int g    = (rem >> 6) & 3;
  int lane = rem & 63;
  if (which == 1 && l == 0 && kc >= 2) return;

  int row = g * 256 + cg * 16 + (lane & 15);
  int k0  = kc * 32 + (lane >> 4) * 8;

  float v[8];
#pragma unroll
  for (int i = 0; i < 8; ++i) {
    int k = k0 + i;
    float x;
    if (which == 0)      x = Whh[(size_t)(l * 1024 + row) * 256 + k];
    else if (l == 0)     x = Wih0[row * 64 + k];
    else                 x = Wih[(size_t)((l - 1) * 1024 + row) * 256 + k];
    v[i] = x;
  }
  u32 pk[4];
#pragma unroll
  for (int i = 0; i < 4; ++i)
    pk[i] = (u32)f2h(v[2 * i]) | ((u32)f2h(v[2 * i + 1]) << 16);
  uint4 val; val.x = pk[0]; val.y = pk[1]; val.z = pk[2]; val.w = pk[3];
  u16* base = (which == 0) ? wfh : wfx;
  u16* dst = base + (size_t)l * WFL9
                  + ((size_t)(kc * 16 + cg) * 4 + g) * 512 + (size_t)lane * 8;
  *(uint4*)dst = val;
}

// ---------------- LSTM layer v11 ----------------
// One block = 16 batch rows, 1024 thr = 16 waves; wave wid owns h-cols
// wid*16+arow across all 4 gates. Per chunk: phase-0 computes xg (v9 structure,
// nt-hinted), then 4 t-steps. T-loop restructured: 16 half-kc units (2 W frags,
// 2 MFMA each), 4-slot LDS ring, exact counted vmcnt (3-unit lookahead).
template <bool L0>
__global__ __launch_bounds__(1024, 4) void lstm_layer_v11(
    const float* __restrict__ X,
    u16* __restrict__ seq,
    const u16* __restrict__ wfx_l,
    const u16* __restrict__ wfh_l,
    u16* __restrict__ xg,             // [NBLK][TCH][1024][16] fp16
    const float* __restrict__ bias) {
  __shared__ __align__(16) u16 Wring[65536];     // 128 KiB: 4 t-loop slots / 2 phase-0 bufs
  __shared__ __align__(16) u16 Ah[16 * 256];     // 8 KiB h matrix (swizzled)

  const int tid  = threadIdx.x;
  const int wid  = tid >> 6;
  const int lane = tid & 63;
  const int bid  = blockIdx.x;
  const int arow = lane & 15;
  const int ahi  = lane >> 4;
  const int j    = wid * 16 + arow;     // owned h column

  *(u32x2*)((char*)Ah + tid * 8) = (u32x2){0, 0};  // h=0 at t=0

  float c[4] = {0.f, 0.f, 0.f, 0.f};
  float bv[4];
#pragma unroll
  for (int g = 0; g < 4; ++g) bv[g] = bias[g * 256 + j];

  u16* wdst0 = Wring + wid * 2048;              // phase-0 buffers (64 KiB halves)
  u16* wdst1 = Wring + 32768 + wid * 2048;
  const size_t laneoff = (size_t)lane * 8;
  u16* xgb = xg + (size_t)bid * 65536;
  u32x2 xr[4];

  __syncthreads();

  for (int tc = 0; tc < T_ / TCH; ++tc) {
    // ================= phase 0: xg for chunk tc (v9 structure + nt) =================
    f32x4 acc0[TCH][4];
#pragma unroll
    for (int rf = 0; rf < TCH; ++rf)
#pragma unroll
      for (int g = 0; g < 4; ++g) {
        acc0[rf][g][0] = bv[g]; acc0[rf][g][1] = bv[g];
        acc0[rf][g][2] = bv[g]; acc0[rf][g][3] = bv[g];
      }

    if constexpr (L0) {
#pragma unroll
      for (int g = 0; g < 4; ++g) {
        gld16(wfx_l + ((size_t)(0 * 16 + wid) * 4 + g) * 512 + laneoff, wdst0 + g * 512);
        gld16(wfx_l + ((size_t)(1 * 16 + wid) * 4 + g) * 512 + laneoff, wdst1 + g * 512);
      }
      asm volatile("s_waitcnt vmcnt(0)" ::: "memory");
      __builtin_amdgcn_sched_barrier(0);
      const float* xb = X + ((size_t)(bid * 16 + arow) * T_ + tc * TCH) * D_ + ahi * 8;
#pragma unroll
      for (int kc = 0; kc < 2; ++kc) {
        const u16* wl = (kc ? wdst1 : wdst0) + lane * 8;
        v8hf af[TCH];
#pragma unroll
        for (int rf = 0; rf < TCH; ++rf) {
          f32x4 u = __builtin_nontemporal_load((const f32x4*)(xb + rf * D_ + kc * 32));
          f32x4 v2 = __builtin_nontemporal_load((const f32x4*)(xb + rf * D_ + kc * 32 + 4));
          v8hf a;
          a[0] = (_Float16)u[0];  a[1] = (_Float16)u[1];
          a[2] = (_Float16)u[2];  a[3] = (_Float16)u[3];
          a[4] = (_Float16)v2[0]; a[5] = (_Float16)v2[1];
          a[6] = (_Float16)v2[2]; a[7] = (_Float16)v2[3];
          af[rf] = a;
        }
#pragma unroll
        for (int g = 0; g < 4; ++g) {
          v8hf w = *(const v8hf*)(const void*)(wl + g * 512);
#pragma unroll
          for (int rf = 0; rf < TCH; ++rf)
            acc0[rf][g] = __builtin_amdgcn_mfma_f32_16x16x32_f16(af[rf], w, acc0[rf][g], 0, 0, 0);
        }
      }
    } else {
      const u16* abase = seq + ((size_t)(bid * T_ + tc * TCH) * 16 + arow) * 256 + ahi * 8;
      v8hf aA[TCH], aB[TCH];
#pragma unroll
      for (int g = 0; g < 4; ++g)
        gld16(wfx_l + ((size_t)(0 * 16 + wid) * 4 + g) * 512 + laneoff, wdst0 + g * 512);
#pragma unroll
      for (int rf = 0; rf < TCH; ++rf)
        aA[rf] = __builtin_nontemporal_load((const v8hf*)(const void*)(abase + rf * 4096));

#pragma unroll
      for (int kc = 0; kc < 8; ++kc) {
        if (kc < 7) {
          u16* nd = ((kc + 1) & 1) ? wdst1 : wdst0;
#pragma unroll
          for (int g = 0; g < 4; ++g)
            gld16(wfx_l + ((size_t)((kc + 1) * 16 + wid) * 4 + g) * 512 + laneoff, nd + g * 512);
          if ((kc & 1) == 0) {
#pragma unroll
            for (int rf = 0; rf < TCH; ++rf)
              aB[rf] = __builtin_nontemporal_load(
                  (const v8hf*)(const void*)(abase + rf * 4096 + (kc + 1) * 32));
          } else {
#pragma unroll
            for (int rf = 0; rf < TCH; ++rf)
              aA[rf] = __builtin_nontemporal_load(
                  (const v8hf*)(const void*)(abase + rf * 4096 + (kc + 1) * 32));
          }
          asm volatile("s_waitcnt vmcnt(8)" ::: "memory");
        } else {
          asm volatile("s_waitcnt vmcnt(0)" ::: "memory");
        }
        __builtin_amdgcn_sched_barrier(0);
        const u16* wl = ((kc & 1) ? wdst1 : wdst0) + lane * 8;
#pragma unroll
        for (int g = 0; g < 4; ++g) {
          v8hf w = *(const v8hf*)(const void*)(wl + g * 512);
#pragma unroll
          for (int rf = 0; rf < TCH; ++rf)
            acc0[rf][g] = __builtin_amdgcn_mfma_f32_16x16x32_f16(
                ((kc & 1) ? aB[rf] : aA[rf]), w, acc0[rf][g], 0, 0, 0);
        }
      }
    }

    // store xg (nt, [t][gatecol][16r]); bias already folded in
#pragma unroll
    for (int rf = 0; rf < TCH; ++rf)
#pragma unroll
      for (int g = 0; g < 4; ++g) {
        u32x2 pk;
        pk[0] = (u32)f2h(acc0[rf][g][0]) | ((u32)f2h(acc0[rf][g][1]) << 16);
        pk[1] = (u32)f2h(acc0[rf][g][2]) | ((u32)f2h(acc0[rf][g][3]) << 16);
        __builtin_nontemporal_store(pk,
            (u32x2*)(xgb + (((size_t)(rf * 1024 + g * 256 + j)) << 4) + ahi * 4));
      }
    __syncthreads();   // xg stores drained; Wring free for t-loop ring

    // xr prologue for tl=0
#pragma unroll
    for (int g = 0; g < 4; ++g)
      xr[g] = __builtin_nontemporal_load(
          (const u32x2*)(xgb + (((size_t)(0 * 1024 + g * 256 + j)) << 4) + ahi * 4));

    // ================= t-steps: 16 half-kc units, 4-slot ring =================
    for (int tl = 0; tl < TCH; ++tl) {
      const int t = tc * TCH + tl;
      f32x4 acc[4];
#pragma unroll
      for (int g = 0; g < 4; ++g) {
        acc[g][0] = h2f((u16)(xr[g][0] & 0xffff));
        acc[g][1] = h2f((u16)(xr[g][0] >> 16));
        acc[g][2] = h2f((u16)(xr[g][1] & 0xffff));
        acc[g][3] = h2f((u16)(xr[g][1] >> 16));
      }

      // ring prologue: units 0,1,2 (queue empty after the step barrier)
#pragma unroll
      for (int u0 = 0; u0 < 3; ++u0) {
        const int kc = u0 >> 1, gh = u0 & 1;
        u16* sb = Wring + (u0 & 3) * 16384 + wid * 1024;
#pragma unroll
        for (int jj = 0; jj < 2; ++jj)
          gld16(wfh_l + ((size_t)(kc * 16 + wid) * 4 + gh * 2 + jj) * 512 + laneoff,
                sb + jj * 512);
      }

      v8hf a{};
#pragma unroll
      for (int u = 0; u < 16; ++u) {
        const int kc = u >> 1, gh = u & 1;
        if (u + 3 <= 15) {
          const int un = u + 3, kn = un >> 1, gn = un & 1;
          u16* sb = Wring + (un & 3) * 16384 + wid * 1024;
#pragma unroll
          for (int jj = 0; jj < 2; ++jj)
            gld16(wfh_l + ((size_t)(kn * 16 + wid) * 4 + gn * 2 + jj) * 512 + laneoff,
                  sb + jj * 512);
        }
        // exact counts: outstanding = 2*min(3, 15-u)
        if (u <= 12)      asm volatile("s_waitcnt vmcnt(6)" ::: "memory");
        else if (u == 13) asm volatile("s_waitcnt vmcnt(4)" ::: "memory");
        else if (u == 14) asm volatile("s_waitcnt vmcnt(2)" ::: "memory");
        else              asm volatile("s_waitcnt vmcnt(0)" ::: "memory");
        __builtin_amdgcn_sched_barrier(0);

        if (gh == 0)
          a = *(const v8hf*)((const char*)Ah + arow * 512 +
                             ((kc * 64 + ahi * 16) ^ ((arow & 7) << 4)));
        const u16* wl = Wring + (u & 3) * 16384 + wid * 1024 + lane * 8;
        v8hf w0 = *(const v8hf*)(const void*)(wl);
        v8hf w1 = *(const v8hf*)(const void*)(wl + 512);
        acc[gh * 2]     = __builtin_amdgcn_mfma_f32_16x16x32_f16(a, w0, acc[gh * 2], 0, 0, 0);
        acc[gh * 2 + 1] = __builtin_amdgcn_mfma_f32_16x16x32_f16(a, w1, acc[gh * 2 + 1], 0, 0, 0);
      }
      __syncthreads();   // all Ah reads done before overwrite (drains vmem too)

      if (tl + 1 < TCH) {   // xr prefetch for next step (drained by barrier below)
#pragma unroll
        for (int g = 0; g < 4; ++g)
          xr[g] = __builtin_nontemporal_load(
              (const u32x2*)(xgb + (((size_t)((tl + 1) * 1024 + g * 256 + j)) << 4) + ahi * 4));
      }

      // phase 3: nonlinearity + state update (lane: col j, rows ahi*4+q)
      u16* sbase = seq + ((((size_t)bid * T_ + t) * 16) << 8) + j;
#pragma unroll
      for (int q = 0; q < 4; ++q) {
        int r = ahi * 4 + q;
        float cn = fsig(acc[1][q]) * c[q] + fsig(acc[0][q]) * ftanh(acc[2][q]);
        c[q] = cn;
        float h = fsig(acc[3][q]) * ftanh(cn);
        u16 hb = f2h(h);
        __builtin_nontemporal_store(hb, sbase + ((size_t)r << 8));
        *(u16*)((char*)Ah + r * 512 + ((j * 2) ^ ((r & 7) << 4))) = hb;
      }
      __syncthreads();   // Ah ready; queue drained for next step's ring
    }
  }
}

// ---------------- tail (encoder / sample / decoder) ----------------
template <int N, int K, bool RELU>
__device__ __forceinline__ void dense(const float (*__restrict__ in)[512],
                                      float (*__restrict__ out)[512],
                                      const float* __restrict__ W,
                                      const float* __restrict__ bg, int tid) {
  for (int e = tid; e < 16 * N; e += 256) {
    int r = e / N, n = e - r * N;
    const float* wr = W + (size_t)n * K;
    const float* ar = in[r];
    float4 acc = {0.f, 0.f, 0.f, 0.f};
    for (int k = 0; k < K; k += 4) {
      float4 wv = *(const float4*)(wr + k);
      float4 av = *(const float4*)(ar + k);
      acc.x = fmaf(wv.x, av.x, acc.x);
      acc.y = fmaf(wv.y, av.y, acc.y);
      acc.z = fmaf(wv.z, av.z, acc.z);
      acc.w = fmaf(wv.w, av.w, acc.w);
    }
    float s = bg[n] + acc.x + acc.y + acc.z + acc.w;
    out[r][n] = RELU ? fmaxf(s, 0.f) : s;
  }
}

template <int K>
__device__ __forceinline__ float dotK(const float* __restrict__ a, const float* __restrict__ w) {
  float4 acc = {0.f, 0.f, 0.f, 0.f};
#pragma unroll
  for (int k = 0; k < K; k += 4) {
    float4 wv = *(const float4*)(w + k);
    float4 av = *(const float4*)(a + k);
    acc.x = fmaf(wv.x, av.x, acc.x);
    acc.y = fmaf(wv.y, av.y, acc.y);
    acc.z = fmaf(wv.z, av.z, acc.z);
    acc.w = fmaf(wv.w, av.w, acc.w);
  }
  return acc.x + acc.y + acc.z + acc.w;
}

struct TailArgs {
  const u16* seq;
  const float *ef1w, *ef1b, *ef2w, *ef2b;
  const float *mean_w, *mean_b, *logvar_w, *logvar_b;
  const float *scale_w, *scale_b, *shape_w, *shape_b;
  const float *df1w, *df1b, *df2w, *df2b, *outw, *outb, *finw, *finb;
  const float *pi, *eps, *u, *choice;
  float* out;
};

__global__ __launch_bounds__(256) void tail_kernel_v11(TailArgs A) {
  __shared__ float a0[16][512];
  __shared__ float a1[16][512];
  const int tid = threadIdx.x, bid = blockIdx.x;

  for (int e = tid; e < 16 * 256; e += 256) {
    int r = e >> 8, jj = e & 255;
    a0[r][jj] = h2f(A.seq[((((size_t)bid * T_ + (T_ - 1)) * 16 + r) << 8) + jj]);
  }
  __syncthreads();

  dense<128, 256, true>(a0, a1, A.ef1w, A.ef1b, tid); __syncthreads();
  dense<64, 128, true>(a1, a0, A.ef2w, A.ef2b, tid);  __syncthreads();

  const float pi = *A.pi;
  for (int e = tid; e < 16 * 64; e += 256) {
    int r = e >> 6, n = e & 63;
    size_t rg = (size_t)bid * 16 + r;
    float m  = dotK<64>(a0[r], A.mean_w   + n * 64) + A.mean_b[n];
    float lv = dotK<64>(a0[r], A.logvar_w + n * 64) + A.logvar_b[n];
    float sc = __expf(dotK<64>(a0[r], A.scale_w + n * 64) + A.scale_b[n]);
    float sh = dotK<64>(a0[r], A.shape_w + n * 64) + A.shape_b[n];
    A.out[196608 + rg * 64 + n] = m;
    A.out[327680 + rg * 64 + n] = lv;
    A.out[458752 + rg * 64 + n] = sc;
    A.out[589824 + rg * 64 + n] = sh;
    float zg = m + A.eps[rg * 64 + n] * __expf(0.5f * lv);
    float L  = log1pf(-A.u[rg * 64 + n]);
    float zp = sc / sh * (__expf(-sh * L) - 1.f);
    a1[r][n] = (A.choice[rg] < pi) ? zg : zp;
  }
  __syncthreads();

  dense<128, 64, true>(a1, a0, A.df1w, A.df1b, tid);   __syncthreads();
  dense<500, 128, true>(a0, a1, A.df2w, A.df2b, tid);  __syncthreads();
  dense<96, 500, false>(a1, a0, A.outw, A.outb, tid);  __syncthreads();
  dense<96, 96, false>(a0, a1, A.finw, A.finb, tid);   __syncthreads();

  for (int e = tid; e < 16 * FUT_; e += 256) {
    int r = e / FUT_, n = e - r * FUT_;
    A.out[((size_t)bid * 16 + r) * FUT_ + n] = a1[r][n];
  }
}

// ---------------- launch ----------------
extern "C" void kernel_launch(void* const* d_in, const int* in_sizes, int n_in,
                              void* d_out, int out_size, void* d_ws, size_t ws_size,
                              hipStream_t stream) {
  (void)in_sizes; (void)n_in; (void)out_size; (void)ws_size;

  const float* X      = (const float*)d_in[0];
  const float* Wih0   = (const float*)d_in[1];
  const float* Wih    = (const float*)d_in[2];
  const float* Whh    = (const float*)d_in[3];
  const float* b      = (const float*)d_in[4];
  const float* ef1w   = (const float*)d_in[5];
  const float* ef1b   = (const float*)d_in[6];
  const float* ef2w   = (const float*)d_in[7];
  const float* ef2b   = (const float*)d_in[8];
  const float* mean_w = (const float*)d_in[9];
  const float* mean_b = (const float*)d_in[10];
  const float* logvar_w = (const float*)d_in[11];
  const float* logvar_b = (const float*)d_in[12];
  const float* scale_w  = (const float*)d_in[13];
  const float* scale_b  = (const float*)d_in[14];
  const float* shape_w  = (const float*)d_in[15];
  const float* shape_b  = (const float*)d_in[16];
  const float* df1w   = (const float*)d_in[17];
  const float* df1b   = (const float*)d_in[18];
  const float* df2w   = (const float*)d_in[19];
  const float* df2b   = (const float*)d_in[20];
  const float* outw   = (const float*)d_in[21];
  const float* outb   = (const float*)d_in[22];
  const float* finw   = (const float*)d_in[23];
  const float* finb   = (const float*)d_in[24];
  const float* pi_g   = (const float*)d_in[25];
  const float* eps    = (const float*)d_in[26];
  const float* u      = (const float*)d_in[27];
  const float* choice = (const float*)d_in[28];

  float* out = (float*)d_out;
  u16* wfh = (u16*)((char*)d_ws + WFH_OFF);
  u16* wfx = (u16*)((char*)d_ws + WFX_OFF);
  u16* xg  = (u16*)((char*)d_ws + XG_OFF);
  u16* seq = (u16*)((char*)d_ws + SEQ2_OFF);

  pack_weights_v11<<<2560, 256, 0, stream>>>(Wih0, Wih, Whh, wfh, wfx);

  lstm_layer_v11<true><<<NBLK, 1024, 0, stream>>>(X, seq, wfx, wfh, xg, b);
  for (int l = 1; l < NL_; ++l)
    lstm_layer_v11<false><<<NBLK, 1024, 0, stream>>>(nullptr, seq,
        wfx + (size_t)l * WFL9, wfh + (size_t)l * WFL9, xg, b + l * 1024);

  TailArgs A;
  A.seq = seq;
  A.ef1w = ef1w; A.ef1b = ef1b; A.ef2w = ef2w; A.ef2b = ef2b;
  A.mean_w = mean_w; A.mean_b = mean_b; A.logvar_w = logvar_w; A.logvar_b = logvar_b;
  A.scale_w = scale_w; A.scale_b = scale_b; A.shape_w = shape_w; A.shape_b = shape_b;
  A.df1w = df1w; A.df1b = df1b; A.df2w = df2w; A.df2b = df2b;
  A.outw = outw; A.outb = outb; A.finw = finw; A.finb = finb;
  A.pi = pi_g; A.eps = eps; A.u = u; A.choice = choice;
  A.out = out;
  tail_kernel_v11<<<NBLK, 256, 0, stream>>>(A);
}

// Round 13
// 11931.809 us; speedup vs baseline: 1.5176x; 1.5176x over previous
//
#include <hip/hip_runtime.h>

typedef unsigned short u16;
typedef unsigned int   u32;
typedef _Float16 v8hf __attribute__((ext_vector_type(8)));
typedef float  f32x4 __attribute__((ext_vector_type(4)));

// ---------------- problem constants ----------------
static constexpr int B_   = 2048;
static constexpr int T_   = 64;
static constexpr int D_   = 64;
static constexpr int H_   = 256;
static constexpr int NL_  = 10;
static constexpr int FUT_ = 96;
static constexpr int NBLK = 128;     // B/16

// ---- workspace layout (bytes), proven fits (R11/R12) ----
static constexpr size_t WFH_OFF  = 0;                     // Whh frags: 10 x 512 KiB
static constexpr size_t WFX_OFF  = 5u << 20;              // Wih frags: 10 x 512 KiB slots
static constexpr size_t XG_OFF   = 10u << 20;             // xg: 128 blk x 128 KiB = 16 MiB
static constexpr size_t SEQ2_OFF = 26u << 20;             // seq: 64 MiB
static constexpr int    WFL9 = 262144;                    // u16 per layer frag slot
static constexpr int    TCH  = 4;                         // timesteps per chunk

// ---------------- small helpers ----------------
__device__ __forceinline__ u16 f2h(float f) {
  _Float16 h = (_Float16)f;
  return __builtin_bit_cast(u16, h);
}
__device__ __forceinline__ float h2f(u16 b) {
  return (float)__builtin_bit_cast(_Float16, b);
}
__device__ __forceinline__ float rcp_(float x) { return __builtin_amdgcn_rcpf(x); }
__device__ __forceinline__ float fsig(float x) { return rcp_(1.f + __expf(-x)); }
__device__ __forceinline__ float ftanh(float x) {
  float e = __expf(-2.f * fabsf(x));
  float t = (1.f - e) * rcp_(1.f + e);
  return copysignf(t, x);
}
__device__ __forceinline__ void gld16(const u16* g, u16* l) {
  __builtin_amdgcn_global_load_lds(
      (const __attribute__((address_space(1))) void*)g,
      (__attribute__((address_space(3))) void*)l,
      16, 0, 0);
}

// ---------------- weight packing (fp16 B-fragment order, [kc][cg][gate]) ----------------
// frag(kc,cg,g)[lane][i] = W[g*256+cg*16+(lane&15)][kc*32+(lane>>4)*8+i]
__global__ void pack_weights_v13(const float* __restrict__ Wih0,
                                 const float* __restrict__ Wih,
                                 const float* __restrict__ Whh,
                                 u16* __restrict__ wfh,
                                 u16* __restrict__ wfx) {
  int gid = blockIdx.x * 256 + threadIdx.x;
  int lw  = gid >> 15;                   // l*2 + which
  if (lw >= NL_ * 2) return;
  int l = lw >> 1, which = lw & 1;
  int rem  = gid & 32767;
  int kc   = rem >> 12;                  // 0..7
  int cg   = (rem >> 8) & 15;
  int g    = (rem >> 6) & 3;
  int lane = rem & 63;
  if (which == 1 && l == 0 && kc >= 2) return;

  int row = g * 256 + cg * 16 + (lane & 15);
  int k0  = kc * 32 + (lane >> 4) * 8;

  float v[8];
#pragma unroll
  for (int i = 0; i < 8; ++i) {
    int k = k0 + i;
    float x;
    if (which == 0)      x = Whh[(size_t)(l * 1024 + row) * 256 + k];
    else if (l == 0)     x = Wih0[row * 64 + k];
    else                 x = Wih[(size_t)((l - 1) * 1024 + row) * 256 + k];
    v[i] = x;
  }
  u32 pk[4];
#pragma unroll
  for (int i = 0; i < 4; ++i)
    pk[i] = (u32)f2h(v[2 * i]) | ((u32)f2h(v[2 * i + 1]) << 16);
  uint4 val; val.x = pk[0]; val.y = pk[1]; val.z = pk[2]; val.w = pk[3];
  u16* base = (which == 0) ? wfh : wfx;
  u16* dst = base + (size_t)l * WFL9
                  + ((size_t)(kc * 16 + cg) * 4 + g) * 512 + (size_t)lane * 8;
  *(uint4*)dst = val;
}

// ---------------- LSTM layer v13 ----------------
// v9 structure (proven) + Whh kc0-3 resident in VGPRs (whr, loaded once per
// layer; Whh is constant over t, so this removes half the per-step streaming
// and its waits). kc4-7 stream through the v9 2-slot LDS ring with exact
// counted vmcnt. No non-temporal hints anywhere. End-of-step barrier added.
template <bool L0>
__global__ __launch_bounds__(1024, 4) void lstm_layer_v13(
    const float* __restrict__ X,
    u16* __restrict__ seq,
    const u16* __restrict__ wfx_l,
    const u16* __restrict__ wfh_l,
    u16* __restrict__ xg,             // [NBLK][TCH][1024][16] fp16
    const float* __restrict__ bias) {
  __shared__ __align__(16) u16 Wring[65536];     // 2 x 64 KiB slots (phase-0 + t-loop)
  __shared__ __align__(16) u16 Ah[16 * 256];     // 8 KiB h matrix (swizzled)

  const int tid  = threadIdx.x;
  const int wid  = tid >> 6;
  const int lane = tid & 63;
  const int bid  = blockIdx.x;
  const int arow = lane & 15;
  const int ahi  = lane >> 4;
  const int j    = wid * 16 + arow;     // owned h column

  *(uint2*)((char*)Ah + tid * 8) = make_uint2(0, 0);   // h = 0 at t = 0

  float c[4] = {0.f, 0.f, 0.f, 0.f};
  float bv[4];
#pragma unroll
  for (int g = 0; g < 4; ++g) bv[g] = bias[g * 256 + j];

  u16* slot0 = Wring + wid * 2048;
  u16* slot1 = Wring + 32768 + wid * 2048;
  const size_t laneoff = (size_t)lane * 8;
  u16* xgb = xg + (size_t)bid * 65536;
  uint2 xr[4];

  // ---- load Whh kc0-3 fragments into registers, once per layer ----
  v8hf whr[4][4];
#pragma unroll
  for (int kc = 0; kc < 4; ++kc)
#pragma unroll
    for (int g = 0; g < 4; ++g)
      whr[kc][g] = *(const v8hf*)(const void*)(
          wfh_l + ((size_t)(kc * 16 + wid) * 4 + g) * 512 + laneoff);

  __syncthreads();

  for (int tc = 0; tc < T_ / TCH; ++tc) {
    // ================= phase 0: xg for chunk tc (v9 structure) =================
    f32x4 acc0[TCH][4];
#pragma unroll
    for (int rf = 0; rf < TCH; ++rf)
#pragma unroll
      for (int g = 0; g < 4; ++g) {
        acc0[rf][g][0] = bv[g]; acc0[rf][g][1] = bv[g];
        acc0[rf][g][2] = bv[g]; acc0[rf][g][3] = bv[g];
      }

    if constexpr (L0) {
#pragma unroll
      for (int g = 0; g < 4; ++g) {
        gld16(wfx_l + ((size_t)(0 * 16 + wid) * 4 + g) * 512 + laneoff, slot0 + g * 512);
        gld16(wfx_l + ((size_t)(1 * 16 + wid) * 4 + g) * 512 + laneoff, slot1 + g * 512);
      }
      asm volatile("s_waitcnt vmcnt(0)" ::: "memory");
      __builtin_amdgcn_sched_barrier(0);
      const float* xb = X + ((size_t)(bid * 16 + arow) * T_ + tc * TCH) * D_ + ahi * 8;
#pragma unroll
      for (int kc = 0; kc < 2; ++kc) {
        const u16* wl = (kc ? slot1 : slot0) + lane * 8;
        v8hf af[TCH];
#pragma unroll
        for (int rf = 0; rf < TCH; ++rf) {
          float4 u = *(const float4*)(xb + rf * D_ + kc * 32);
          float4 v2 = *(const float4*)(xb + rf * D_ + kc * 32 + 4);
          v8hf a;
          a[0] = (_Float16)u.x;  a[1] = (_Float16)u.y;
          a[2] = (_Float16)u.z;  a[3] = (_Float16)u.w;
          a[4] = (_Float16)v2.x; a[5] = (_Float16)v2.y;
          a[6] = (_Float16)v2.z; a[7] = (_Float16)v2.w;
          af[rf] = a;
        }
#pragma unroll
        for (int g = 0; g < 4; ++g) {
          v8hf w = *(const v8hf*)(const void*)(wl + g * 512);
#pragma unroll
          for (int rf = 0; rf < TCH; ++rf)
            acc0[rf][g] = __builtin_amdgcn_mfma_f32_16x16x32_f16(af[rf], w, acc0[rf][g], 0, 0, 0);
        }
      }
    } else {
      const u16* abase = seq + ((size_t)(bid * T_ + tc * TCH) * 16 + arow) * 256 + ahi * 8;
      v8hf aA[TCH], aB[TCH];
#pragma unroll
      for (int g = 0; g < 4; ++g)
        gld16(wfx_l + ((size_t)(0 * 16 + wid) * 4 + g) * 512 + laneoff, slot0 + g * 512);
#pragma unroll
      for (int rf = 0; rf < TCH; ++rf)
        aA[rf] = *(const v8hf*)(const void*)(abase + rf * 4096);

#pragma unroll
      for (int kc = 0; kc < 8; ++kc) {
        if (kc < 7) {
          u16* nd = ((kc + 1) & 1) ? slot1 : slot0;
#pragma unroll
          for (int g = 0; g < 4; ++g)
            gld16(wfx_l + ((size_t)((kc + 1) * 16 + wid) * 4 + g) * 512 + laneoff, nd + g * 512);
          if ((kc & 1) == 0) {
#pragma unroll
            for (int rf = 0; rf < TCH; ++rf)
              aB[rf] = *(const v8hf*)(const void*)(abase + rf * 4096 + (kc + 1) * 32);
          } else {
#pragma unroll
            for (int rf = 0; rf < TCH; ++rf)
              aA[rf] = *(const v8hf*)(const void*)(abase + rf * 4096 + (kc + 1) * 32);
          }
          asm volatile("s_waitcnt vmcnt(8)" ::: "memory");
        } else {
          asm volatile("s_waitcnt vmcnt(0)" ::: "memory");
        }
        __builtin_amdgcn_sched_barrier(0);
        const u16* wl = ((kc & 1) ? slot1 : slot0) + lane * 8;
#pragma unroll
        for (int g = 0; g < 4; ++g) {
          v8hf w = *(const v8hf*)(const void*)(wl + g * 512);
#pragma unroll
          for (int rf = 0; rf < TCH; ++rf)
            acc0[rf][g] = __builtin_amdgcn_mfma_f32_16x16x32_f16(
                ((kc & 1) ? aB[rf] : aA[rf]), w, acc0[rf][g], 0, 0, 0);
        }
      }
    }

    // store xg ([t][gatecol][16r]); bias already folded in
#pragma unroll
    for (int rf = 0; rf < TCH; ++rf)
#pragma unroll
      for (int g = 0; g < 4; ++g) {
        uint2 pk;
        pk.x = (u32)f2h(acc0[rf][g][0]) | ((u32)f2h(acc0[rf][g][1]) << 16);
        pk.y = (u32)f2h(acc0[rf][g][2]) | ((u32)f2h(acc0[rf][g][3]) << 16);
        *(uint2*)(xgb + (((size_t)(rf * 1024 + g * 256 + j)) << 4) + ahi * 4) = pk;
      }
    __syncthreads();   // xg visible; Wring free for t-loop

    // xr prologue for tl=0
#pragma unroll
    for (int g = 0; g < 4; ++g)
      xr[g] = *(const uint2*)(xgb + (((size_t)(0 * 1024 + g * 256 + j)) << 4) + ahi * 4);

    // ================= t-steps =================
    for (int tl = 0; tl < TCH; ++tl) {
      const int t = tc * TCH + tl;
      f32x4 acc[4];
#pragma unroll
      for (int g = 0; g < 4; ++g) {
        acc[g][0] = h2f((u16)(xr[g].x & 0xffff));
        acc[g][1] = h2f((u16)(xr[g].x >> 16));
        acc[g][2] = h2f((u16)(xr[g].y & 0xffff));
        acc[g][3] = h2f((u16)(xr[g].y >> 16));
      }

      // issue kc4 + kc5 DMAs up front (queue empty after step barrier)
#pragma unroll
      for (int g = 0; g < 4; ++g)
        gld16(wfh_l + ((size_t)(4 * 16 + wid) * 4 + g) * 512 + laneoff, slot0 + g * 512);
#pragma unroll
      for (int g = 0; g < 4; ++g)
        gld16(wfh_l + ((size_t)(5 * 16 + wid) * 4 + g) * 512 + laneoff, slot1 + g * 512);

      // kc0-3 from registers -- no memory waits; covers DMA flight time
#pragma unroll
      for (int kc = 0; kc < 4; ++kc) {
        v8hf a = *(const v8hf*)((const char*)Ah + arow * 512 +
                                ((kc * 64 + ahi * 16) ^ ((arow & 7) << 4)));
#pragma unroll
        for (int g = 0; g < 4; ++g)
          acc[g] = __builtin_amdgcn_mfma_f32_16x16x32_f16(a, whr[kc][g], acc[g], 0, 0, 0);
      }

      // kc4 (slot0): outstanding kc4(4)+kc5(4)=8 -> wait(4) = kc4 landed
      asm volatile("s_waitcnt vmcnt(4)" ::: "memory");
      __builtin_amdgcn_sched_barrier(0);
      {
        v8hf a = *(const v8hf*)((const char*)Ah + arow * 512 +
                                ((4 * 64 + ahi * 16) ^ ((arow & 7) << 4)));
        const u16* wl = slot0 + lane * 8;
#pragma unroll
        for (int g = 0; g < 4; ++g) {
          v8hf w = *(const v8hf*)(const void*)(wl + g * 512);
          acc[g] = __builtin_amdgcn_mfma_f32_16x16x32_f16(a, w, acc[g], 0, 0, 0);
        }
      }
      // issue kc6 -> slot0 (kc4 LDS reads already executed)
#pragma unroll
      for (int g = 0; g < 4; ++g)
        gld16(wfh_l + ((size_t)(6 * 16 + wid) * 4 + g) * 512 + laneoff, slot0 + g * 512);
      // kc5 (slot1): newest 4 are kc6 -> wait(4) = kc5 landed
      asm volatile("s_waitcnt vmcnt(4)" ::: "memory");
      __builtin_amdgcn_sched_barrier(0);
      {
        v8hf a = *(const v8hf*)((const char*)Ah + arow * 512 +
                                ((5 * 64 + ahi * 16) ^ ((arow & 7) << 4)));
        const u16* wl = slot1 + lane * 8;
#pragma unroll
        for (int g = 0; g < 4; ++g) {
          v8hf w = *(const v8hf*)(const void*)(wl + g * 512);
          acc[g] = __builtin_amdgcn_mfma_f32_16x16x32_f16(a, w, acc[g], 0, 0, 0);
        }
      }
      // issue kc7 -> slot1
#pragma unroll
      for (int g = 0; g < 4; ++g)
        gld16(wfh_l + ((size_t)(7 * 16 + wid) * 4 + g) * 512 + laneoff, slot1 + g * 512);
      // kc6: wait(4) = kc6 landed (kc7 outstanding)
      asm volatile("s_waitcnt vmcnt(4)" ::: "memory");
      __builtin_amdgcn_sched_barrier(0);
      {
        v8hf a = *(const v8hf*)((const char*)Ah + arow * 512 +
                                ((6 * 64 + ahi * 16) ^ ((arow & 7) << 4)));
        const u16* wl = slot0 + lane * 8;
#pragma unroll
        for (int g = 0; g < 4; ++g) {
          v8hf w = *(const v8hf*)(const void*)(wl + g * 512);
          acc[g] = __builtin_amdgcn_mfma_f32_16x16x32_f16(a, w, acc[g], 0, 0, 0);
        }
      }
      // kc7: drain
      asm volatile("s_waitcnt vmcnt(0)" ::: "memory");
      __builtin_amdgcn_sched_barrier(0);
      {
        v8hf a = *(const v8hf*)((const char*)Ah + arow * 512 +
                                ((7 * 64 + ahi * 16) ^ ((arow & 7) << 4)));
        const u16* wl = slot1 + lane * 8;
#pragma unroll
        for (int g = 0; g < 4; ++g) {
          v8hf w = *(const v8hf*)(const void*)(wl + g * 512);
          acc[g] = __builtin_amdgcn_mfma_f32_16x16x32_f16(a, w, acc[g], 0, 0, 0);
        }
      }
      __syncthreads();   // all Ah reads done before overwrite

      if (tl + 1 < TCH) {   // xr prefetch for next step
#pragma unroll
        for (int g = 0; g < 4; ++g)
          xr[g] = *(const uint2*)(xgb + (((size_t)((tl + 1) * 1024 + g * 256 + j)) << 4) + ahi * 4);
      }

      // phase 3: nonlinearity + state update (lane: col j, rows ahi*4+q)
      u16* sbase = seq + ((((size_t)bid * T_ + t) * 16) << 8) + j;
#pragma unroll
      for (int q = 0; q < 4; ++q) {
        int r = ahi * 4 + q;
        float cn = fsig(acc[1][q]) * c[q] + fsig(acc[0][q]) * ftanh(acc[2][q]);
        c[q] = cn;
        float h = fsig(acc[3][q]) * ftanh(cn);
        u16 hb = f2h(h);
        sbase[(size_t)r << 8] = hb;
        *(u16*)((char*)Ah + r * 512 + ((j * 2) ^ ((r & 7) << 4))) = hb;
      }
      __syncthreads();   // Ah complete for next step's reads
    }
  }
}

// ---------------- tail (encoder / sample / decoder) ----------------
template <int N, int K, bool RELU>
__device__ __forceinline__ void dense(const float (*__restrict__ in)[512],
                                      float (*__restrict__ out)[512],
                                      const float* __restrict__ W,
                                      const float* __restrict__ bg, int tid) {
  for (int e = tid; e < 16 * N; e += 256) {
    int r = e / N, n = e - r * N;
    const float* wr = W + (size_t)n * K;
    const float* ar = in[r];
    float4 acc = {0.f, 0.f, 0.f, 0.f};
    for (int k = 0; k < K; k += 4) {
      float4 wv = *(const float4*)(wr + k);
      float4 av = *(const float4*)(ar + k);
      acc.x = fmaf(wv.x, av.x, acc.x);
      acc.y = fmaf(wv.y, av.y, acc.y);
      acc.z = fmaf(wv.z, av.z, acc.z);
      acc.w = fmaf(wv.w, av.w, acc.w);
    }
    float s = bg[n] + acc.x + acc.y + acc.z + acc.w;
    out[r][n] = RELU ? fmaxf(s, 0.f) : s;
  }
}

template <int K>
__device__ __forceinline__ float dotK(const float* __restrict__ a, const float* __restrict__ w) {
  float4 acc = {0.f, 0.f, 0.f, 0.f};
#pragma unroll
  for (int k = 0; k < K; k += 4) {
    float4 wv = *(const float4*)(w + k);
    float4 av = *(const float4*)(a + k);
    acc.x = fmaf(wv.x, av.x, acc.x);
    acc.y = fmaf(wv.y, av.y, acc.y);
    acc.z = fmaf(wv.z, av.z, acc.z);
    acc.w = fmaf(wv.w, av.w, acc.w);
  }
  return acc.x + acc.y + acc.z + acc.w;
}

struct TailArgs {
  const u16* seq;
  const float *ef1w, *ef1b, *ef2w, *ef2b;
  const float *mean_w, *mean_b, *logvar_w, *logvar_b;
  const float *scale_w, *scale_b, *shape_w, *shape_b;
  const float *df1w, *df1b, *df2w, *df2b, *outw, *outb, *finw, *finb;
  const float *pi, *eps, *u, *choice;
  float* out;
};

__global__ __launch_bounds__(256) void tail_kernel_v13(TailArgs A) {
  __shared__ float a0[16][512];
  __shared__ float a1[16][512];
  const int tid = threadIdx.x, bid = blockIdx.x;

  for (int e = tid; e < 16 * 256; e += 256) {
    int r = e >> 8, jj = e & 255;
    a0[r][jj] = h2f(A.seq[((((size_t)bid * T_ + (T_ - 1)) * 16 + r) << 8) + jj]);
  }
  __syncthreads();

  dense<128, 256, true>(a0, a1, A.ef1w, A.ef1b, tid); __syncthreads();
  dense<64, 128, true>(a1, a0, A.ef2w, A.ef2b, tid);  __syncthreads();

  const float pi = *A.pi;
  for (int e = tid; e < 16 * 64; e += 256) {
    int r = e >> 6, n = e & 63;
    size_t rg = (size_t)bid * 16 + r;
    float m  = dotK<64>(a0[r], A.mean_w   + n * 64) + A.mean_b[n];
    float lv = dotK<64>(a0[r], A.logvar_w + n * 64) + A.logvar_b[n];
    float sc = __expf(dotK<64>(a0[r], A.scale_w + n * 64) + A.scale_b[n]);
    float sh = dotK<64>(a0[r], A.shape_w + n * 64) + A.shape_b[n];
    A.out[196608 + rg * 64 + n] = m;
    A.out[327680 + rg * 64 + n] = lv;
    A.out[458752 + rg * 64 + n] = sc;
    A.out[589824 + rg * 64 + n] = sh;
    float zg = m + A.eps[rg * 64 + n] * __expf(0.5f * lv);
    float L  = log1pf(-A.u[rg * 64 + n]);
    float zp = sc / sh * (__expf(-sh * L) - 1.f);
    a1[r][n] = (A.choice[rg] < pi) ? zg : zp;
  }
  __syncthreads();

  dense<128, 64, true>(a1, a0, A.df1w, A.df1b, tid);   __syncthreads();
  dense<500, 128, true>(a0, a1, A.df2w, A.df2b, tid);  __syncthreads();
  dense<96, 500, false>(a1, a0, A.outw, A.outb, tid);  __syncthreads();
  dense<96, 96, false>(a0, a1, A.finw, A.finb, tid);   __syncthreads();

  for (int e = tid; e < 16 * FUT_; e += 256) {
    int r = e / FUT_, n = e - r * FUT_;
    A.out[((size_t)bid * 16 + r) * FUT_ + n] = a1[r][n];
  }
}

// ---------------- launch ----------------
extern "C" void kernel_launch(void* const* d_in, const int* in_sizes, int n_in,
                              void* d_out, int out_size, void* d_ws, size_t ws_size,
                              hipStream_t stream) {
  (void)in_sizes; (void)n_in; (void)out_size; (void)ws_size;

  const float* X      = (const float*)d_in[0];
  const float* Wih0   = (const float*)d_in[1];
  const float* Wih    = (const float*)d_in[2];
  const float* Whh    = (const float*)d_in[3];
  const float* b      = (const float*)d_in[4];
  const float* ef1w   = (const float*)d_in[5];
  const float* ef1b   = (const float*)d_in[6];
  const float* ef2w   = (const float*)d_in[7];
  const float* ef2b   = (const float*)d_in[8];
  const float* mean_w = (const float*)d_in[9];
  const float* mean_b = (const float*)d_in[10];
  const float* logvar_w = (const float*)d_in[11];
  const float* logvar_b = (const float*)d_in[12];
  const float* scale_w  = (const float*)d_in[13];
  const float* scale_b  = (const float*)d_in[14];
  const float* shape_w  = (const float*)d_in[15];
  const float* shape_b  = (const float*)d_in[16];
  const float* df1w   = (const float*)d_in[17];
  const float* df1b   = (const float*)d_in[18];
  const float* df2w   = (const float*)d_in[19];
  const float* df2b   = (const float*)d_in[20];
  const float* outw   = (const float*)d_in[21];
  const float* outb   = (const float*)d_in[22];
  const float* finw   = (const float*)d_in[23];
  const float* finb   = (const float*)d_in[24];
  const float* pi_g   = (const float*)d_in[25];
  const float* eps    = (const float*)d_in[26];
  const float* u      = (const float*)d_in[27];
  const float* choice = (const float*)d_in[28];

  float* out = (float*)d_out;
  u16* wfh = (u16*)((char*)d_ws + WFH_OFF);
  u16* wfx = (u16*)((char*)d_ws + WFX_OFF);
  u16* xg  = (u16*)((char*)d_ws + XG_OFF);
  u16* seq = (u16*)((char*)d_ws + SEQ2_OFF);

  pack_weights_v13<<<2560, 256, 0, stream>>>(Wih0, Wih, Whh, wfh, wfx);

  lstm_layer_v13<true><<<NBLK, 1024, 0, stream>>>(X, seq, wfx, wfh, xg, b);
  for (int l = 1; l < NL_; ++l)
    lstm_layer_v13<false><<<NBLK, 1024, 0, stream>>>(nullptr, seq,
        wfx + (size_t)l * WFL9, wfh + (size_t)l * WFL9, xg, b + l * 1024);

  TailArgs A;
  A.seq = seq;
  A.ef1w = ef1w; A.ef1b = ef1b; A.ef2w = ef2w; A.ef2b = ef2b;
  A.mean_w = mean_w; A.mean_b = mean_b; A.logvar_w = logvar_w; A.logvar_b = logvar_b;
  A.scale_w = scale_w; A.scale_b = scale_b; A.shape_w = shape_w; A.shape_b = shape_b;
  A.df1w = df1w; A.df1b = df1b; A.df2w = df2w; A.df2b = df2b;
  A.outw = outw; A.outb = outb; A.finw = finw; A.finb = finb;
  A.pi = pi_g; A.eps = eps; A.u = u; A.choice = choice;
  A.out = out;
  tail_kernel_v13<<<NBLK, 256, 0, stream>>>(A);
}

// Round 14
// 11087.099 us; speedup vs baseline: 1.6333x; 1.0762x over previous
//
#include <hip/hip_runtime.h>

typedef unsigned short u16;
typedef unsigned int   u32;
typedef _Float16 v8hf __attribute__((ext_vector_type(8)));
typedef float  f32x4 __attribute__((ext_vector_type(4)));

// ---------------- problem constants ----------------
static constexpr int B_   = 2048;
static constexpr int T_   = 64;
static constexpr int D_   = 64;
static constexpr int H_   = 256;
static constexpr int NL_  = 10;
static constexpr int FUT_ = 96;
static constexpr int NBLK = 128;     // B/16

// ---- workspace layout (bytes), proven fits ----
static constexpr size_t WFH_OFF  = 0;                     // Whh frags: 10 x 512 KiB
static constexpr size_t WFX_OFF  = 5u << 20;              // Wih frags: 10 x 512 KiB slots
static constexpr size_t SEQ2_OFF = 26u << 20;             // seq: 64 MiB (xg region now unused)
static constexpr int    WFL9 = 262144;                    // u16 per layer frag slot
static constexpr int    TCH  = 4;                         // timesteps per chunk

// ---------------- small helpers ----------------
__device__ __forceinline__ u16 f2h(float f) {
  _Float16 h = (_Float16)f;
  return __builtin_bit_cast(u16, h);
}
__device__ __forceinline__ float h2f(u16 b) {
  return (float)__builtin_bit_cast(_Float16, b);
}
__device__ __forceinline__ float rcp_(float x) { return __builtin_amdgcn_rcpf(x); }
__device__ __forceinline__ float fsig(float x) { return rcp_(1.f + __expf(-x)); }
__device__ __forceinline__ float ftanh(float x) {
  float e = __expf(-2.f * fabsf(x));
  float t = (1.f - e) * rcp_(1.f + e);
  return copysignf(t, x);
}
__device__ __forceinline__ void gld16(const u16* g, u16* l) {
  __builtin_amdgcn_global_load_lds(
      (const __attribute__((address_space(1))) void*)g,
      (__attribute__((address_space(3))) void*)l,
      16, 0, 0);
}

// ---------------- weight packing (fp16 B-fragment order, [kc][cg][gate]) ----------------
// frag(kc,cg,g)[lane][i] = W[g*256+cg*16+(lane&15)][kc*32+(lane>>4)*8+i]
__global__ void pack_weights_v14(const float* __restrict__ Wih0,
                                 const float* __restrict__ Wih,
                                 const float* __restrict__ Whh,
                                 u16* __restrict__ wfh,
                                 u16* __restrict__ wfx) {
  int gid = blockIdx.x * 256 + threadIdx.x;
  int lw  = gid >> 15;                   // l*2 + which
  if (lw >= NL_ * 2) return;
  int l = lw >> 1, which = lw & 1;
  int rem  = gid & 32767;
  int kc   = rem >> 12;                  // 0..7
  int cg   = (rem >> 8) & 15;
  int g    = (rem >> 6) & 3;
  int lane = rem & 63;
  if (which == 1 && l == 0 && kc >= 2) return;

  int row = g * 256 + cg * 16 + (lane & 15);
  int k0  = kc * 32 + (lane >> 4) * 8;

  float v[8];
#pragma unroll
  for (int i = 0; i < 8; ++i) {
    int k = k0 + i;
    float x;
    if (which == 0)      x = Whh[(size_t)(l * 1024 + row) * 256 + k];
    else if (l == 0)     x = Wih0[row * 64 + k];
    else                 x = Wih[(size_t)((l - 1) * 1024 + row) * 256 + k];
    v[i] = x;
  }
  u32 pk[4];
#pragma unroll
  for (int i = 0; i < 4; ++i)
    pk[i] = (u32)f2h(v[2 * i]) | ((u32)f2h(v[2 * i + 1]) << 16);
  uint4 val; val.x = pk[0]; val.y = pk[1]; val.z = pk[2]; val.w = pk[3];
  u16* base = (which == 0) ? wfh : wfx;
  u16* dst = base + (size_t)l * WFL9
                  + ((size_t)(kc * 16 + cg) * 4 + g) * 512 + (size_t)lane * 8;
  *(uint4*)dst = val;
}

// ---------------- LSTM layer v14 ----------------
// v9 structure + (1) xg kept in registers (packed fp16, MFMA results can't be
// rematerialized by regalloc -- rule learned R8/R9/R13), t-steps fully
// unrolled for static indexing; (2) 2-kc DMA lookahead: kc0/kc1 for step t+1
// issued before the end-of-step barrier (barrier drain hides flight under
// phase-3), uniform counted vmcnt(4) with 8 outstanding in steady state.
// No non-temporal hints (R12 lesson). Wave-private W slots -> no extra barriers.
template <bool L0>
__global__ __launch_bounds__(1024, 4) void lstm_layer_v14(
    const float* __restrict__ X,
    u16* __restrict__ seq,
    const u16* __restrict__ wfx_l,
    const u16* __restrict__ wfh_l,
    const float* __restrict__ bias) {
  __shared__ __align__(16) u16 Wring[65536];     // 2 x 64 KiB slots (16 waves x 4 KiB)
  __shared__ __align__(16) u16 Ah[16 * 256];     // 8 KiB h matrix (swizzled)

  const int tid  = threadIdx.x;
  const int wid  = tid >> 6;
  const int lane = tid & 63;
  const int bid  = blockIdx.x;
  const int arow = lane & 15;
  const int ahi  = lane >> 4;
  const int j    = wid * 16 + arow;     // owned h column

  *(uint2*)((char*)Ah + tid * 8) = make_uint2(0, 0);   // h = 0 at t = 0

  float c[4] = {0.f, 0.f, 0.f, 0.f};
  float bv[4];
#pragma unroll
  for (int g = 0; g < 4; ++g) bv[g] = bias[g * 256 + j];

  u16* slot0 = Wring + wid * 2048;
  u16* slot1 = Wring + 32768 + wid * 2048;
  const size_t laneoff = (size_t)lane * 8;

  __syncthreads();

  for (int tc = 0; tc < T_ / TCH; ++tc) {
    // ================= phase 0: xg for chunk tc (v9 schedule, acc in regs) =================
    f32x4 acc0[TCH][4];
#pragma unroll
    for (int rf = 0; rf < TCH; ++rf)
#pragma unroll
      for (int g = 0; g < 4; ++g) {
        acc0[rf][g][0] = bv[g]; acc0[rf][g][1] = bv[g];
        acc0[rf][g][2] = bv[g]; acc0[rf][g][3] = bv[g];
      }

    if constexpr (L0) {
#pragma unroll
      for (int g = 0; g < 4; ++g) {
        gld16(wfx_l + ((size_t)(0 * 16 + wid) * 4 + g) * 512 + laneoff, slot0 + g * 512);
        gld16(wfx_l + ((size_t)(1 * 16 + wid) * 4 + g) * 512 + laneoff, slot1 + g * 512);
      }
      asm volatile("s_waitcnt vmcnt(0)" ::: "memory");
      __builtin_amdgcn_sched_barrier(0);
      const float* xb = X + ((size_t)(bid * 16 + arow) * T_ + tc * TCH) * D_ + ahi * 8;
#pragma unroll
      for (int kc = 0; kc < 2; ++kc) {
        const u16* wl = (kc ? slot1 : slot0) + lane * 8;
        v8hf af[TCH];
#pragma unroll
        for (int rf = 0; rf < TCH; ++rf) {
          float4 u = *(const float4*)(xb + rf * D_ + kc * 32);
          float4 v2 = *(const float4*)(xb + rf * D_ + kc * 32 + 4);
          v8hf a;
          a[0] = (_Float16)u.x;  a[1] = (_Float16)u.y;
          a[2] = (_Float16)u.z;  a[3] = (_Float16)u.w;
          a[4] = (_Float16)v2.x; a[5] = (_Float16)v2.y;
          a[6] = (_Float16)v2.z; a[7] = (_Float16)v2.w;
          af[rf] = a;
        }
#pragma unroll
        for (int g = 0; g < 4; ++g) {
          v8hf w = *(const v8hf*)(const void*)(wl + g * 512);
#pragma unroll
          for (int rf = 0; rf < TCH; ++rf)
            acc0[rf][g] = __builtin_amdgcn_mfma_f32_16x16x32_f16(af[rf], w, acc0[rf][g], 0, 0, 0);
        }
      }
    } else {
      const u16* abase = seq + ((size_t)(bid * T_ + tc * TCH) * 16 + arow) * 256 + ahi * 8;
      v8hf aA[TCH], aB[TCH];
#pragma unroll
      for (int g = 0; g < 4; ++g)
        gld16(wfx_l + ((size_t)(0 * 16 + wid) * 4 + g) * 512 + laneoff, slot0 + g * 512);
#pragma unroll
      for (int rf = 0; rf < TCH; ++rf)
        aA[rf] = *(const v8hf*)(const void*)(abase + rf * 4096);

#pragma unroll
      for (int kc = 0; kc < 8; ++kc) {
        if (kc < 7) {
          u16* nd = ((kc + 1) & 1) ? slot1 : slot0;
#pragma unroll
          for (int g = 0; g < 4; ++g)
            gld16(wfx_l + ((size_t)((kc + 1) * 16 + wid) * 4 + g) * 512 + laneoff, nd + g * 512);
          if ((kc & 1) == 0) {
#pragma unroll
            for (int rf = 0; rf < TCH; ++rf)
              aB[rf] = *(const v8hf*)(const void*)(abase + rf * 4096 + (kc + 1) * 32);
          } else {
#pragma unroll
            for (int rf = 0; rf < TCH; ++rf)
              aA[rf] = *(const v8hf*)(const void*)(abase + rf * 4096 + (kc + 1) * 32);
          }
          asm volatile("s_waitcnt vmcnt(8)" ::: "memory");
        } else {
          asm volatile("s_waitcnt vmcnt(0)" ::: "memory");
        }
        __builtin_amdgcn_sched_barrier(0);
        const u16* wl = ((kc & 1) ? slot1 : slot0) + lane * 8;
#pragma unroll
        for (int g = 0; g < 4; ++g) {
          v8hf w = *(const v8hf*)(const void*)(wl + g * 512);
#pragma unroll
          for (int rf = 0; rf < TCH; ++rf)
            acc0[rf][g] = __builtin_amdgcn_mfma_f32_16x16x32_f16(
                ((kc & 1) ? aB[rf] : aA[rf]), w, acc0[rf][g], 0, 0, 0);
        }
      }
    }

    // stage Whh kc0/kc1 for the first t-step (slots free: last Wih reads done)
#pragma unroll
    for (int g = 0; g < 4; ++g)
      gld16(wfh_l + ((size_t)(0 * 16 + wid) * 4 + g) * 512 + laneoff, slot0 + g * 512);
#pragma unroll
    for (int g = 0; g < 4; ++g)
      gld16(wfh_l + ((size_t)(1 * 16 + wid) * 4 + g) * 512 + laneoff, slot1 + g * 512);

    // pack xg into registers (same fp16 round-trip as the old xg path)
    uint2 xr[TCH][4];
#pragma unroll
    for (int rf = 0; rf < TCH; ++rf)
#pragma unroll
      for (int g = 0; g < 4; ++g) {
        xr[rf][g].x = (u32)f2h(acc0[rf][g][0]) | ((u32)f2h(acc0[rf][g][1]) << 16);
        xr[rf][g].y = (u32)f2h(acc0[rf][g][2]) | ((u32)f2h(acc0[rf][g][3]) << 16);
      }

    // ================= t-steps (fully unrolled; static xr indexing) =================
#pragma unroll
    for (int tl = 0; tl < TCH; ++tl) {
      const int t = tc * TCH + tl;
      f32x4 acc[4];
#pragma unroll
      for (int g = 0; g < 4; ++g) {
        acc[g][0] = h2f((u16)(xr[tl][g].x & 0xffff));
        acc[g][1] = h2f((u16)(xr[tl][g].x >> 16));
        acc[g][2] = h2f((u16)(xr[tl][g].y & 0xffff));
        acc[g][3] = h2f((u16)(xr[tl][g].y >> 16));
      }

      // 8 kc units; slot = kc&1; issue kc+2 after consuming kc; uniform vmcnt(4)
#pragma unroll
      for (int kc = 0; kc < 8; ++kc) {
        if (kc < 7) asm volatile("s_waitcnt vmcnt(4)" ::: "memory");
        else        asm volatile("s_waitcnt vmcnt(0)" ::: "memory");
        __builtin_amdgcn_sched_barrier(0);

        v8hf a = *(const v8hf*)((const char*)Ah + arow * 512 +
                                ((kc * 64 + ahi * 16) ^ ((arow & 7) << 4)));
        const u16* wl = ((kc & 1) ? slot1 : slot0) + lane * 8;
#pragma unroll
        for (int g = 0; g < 4; ++g) {
          v8hf w = *(const v8hf*)(const void*)(wl + g * 512);
          acc[g] = __builtin_amdgcn_mfma_f32_16x16x32_f16(a, w, acc[g], 0, 0, 0);
        }
        // refill the slot just consumed with kc+2 (safe: MFMA's lgkm wait
        // guarantees the ds_reads executed before this DMA can land)
        if (kc < 6) {
          u16* nd = (kc & 1) ? slot1 : slot0;
#pragma unroll
          for (int g = 0; g < 4; ++g)
            gld16(wfh_l + ((size_t)((kc + 2) * 16 + wid) * 4 + g) * 512 + laneoff,
                  nd + g * 512);
        }
      }
      __syncthreads();   // all Ah reads done before overwrite (drains vmem)

      // prefetch next step's kc0/kc1 (flight hidden under phase-3 + barrier)
      if (tl + 1 < TCH) {
#pragma unroll
        for (int g = 0; g < 4; ++g)
          gld16(wfh_l + ((size_t)(0 * 16 + wid) * 4 + g) * 512 + laneoff, slot0 + g * 512);
#pragma unroll
        for (int g = 0; g < 4; ++g)
          gld16(wfh_l + ((size_t)(1 * 16 + wid) * 4 + g) * 512 + laneoff, slot1 + g * 512);
      }

      // phase 3: nonlinearity + state update (lane: col j, rows ahi*4+q)
      u16* sbase = seq + ((((size_t)bid * T_ + t) * 16) << 8) + j;
#pragma unroll
      for (int q = 0; q < 4; ++q) {
        int r = ahi * 4 + q;
        float cn = fsig(acc[1][q]) * c[q] + fsig(acc[0][q]) * ftanh(acc[2][q]);
        c[q] = cn;
        float h = fsig(acc[3][q]) * ftanh(cn);
        u16 hb = f2h(h);
        sbase[(size_t)r << 8] = hb;
        *(u16*)((char*)Ah + r * 512 + ((j * 2) ^ ((r & 7) << 4))) = hb;
      }
      __syncthreads();   // Ah complete; barrier drain lands kc0/kc1 prefetch
    }
  }
}

// ---------------- tail (encoder / sample / decoder) ----------------
template <int N, int K, bool RELU>
__device__ __forceinline__ void dense(const float (*__restrict__ in)[512],
                                      float (*__restrict__ out)[512],
                                      const float* __restrict__ W,
                                      const float* __restrict__ bg, int tid) {
  for (int e = tid; e < 16 * N; e += 256) {
    int r = e / N, n = e - r * N;
    const float* wr = W + (size_t)n * K;
    const float* ar = in[r];
    float4 acc = {0.f, 0.f, 0.f, 0.f};
    for (int k = 0; k < K; k += 4) {
      float4 wv = *(const float4*)(wr + k);
      float4 av = *(const float4*)(ar + k);
      acc.x = fmaf(wv.x, av.x, acc.x);
      acc.y = fmaf(wv.y, av.y, acc.y);
      acc.z = fmaf(wv.z, av.z, acc.z);
      acc.w = fmaf(wv.w, av.w, acc.w);
    }
    float s = bg[n] + acc.x + acc.y + acc.z + acc.w;
    out[r][n] = RELU ? fmaxf(s, 0.f) : s;
  }
}

template <int K>
__device__ __forceinline__ float dotK(const float* __restrict__ a, const float* __restrict__ w) {
  float4 acc = {0.f, 0.f, 0.f, 0.f};
#pragma unroll
  for (int k = 0; k < K; k += 4) {
    float4 wv = *(const float4*)(w + k);
    float4 av = *(const float4*)(a + k);
    acc.x = fmaf(wv.x, av.x, acc.x);
    acc.y = fmaf(wv.y, av.y, acc.y);
    acc.z = fmaf(wv.z, av.z, acc.z);
    acc.w = fmaf(wv.w, av.w, acc.w);
  }
  return acc.x + acc.y + acc.z + acc.w;
}

struct TailArgs {
  const u16* seq;
  const float *ef1w, *ef1b, *ef2w, *ef2b;
  const float *mean_w, *mean_b, *logvar_w, *logvar_b;
  const float *scale_w, *scale_b, *shape_w, *shape_b;
  const float *df1w, *df1b, *df2w, *df2b, *outw, *outb, *finw, *finb;
  const float *pi, *eps, *u, *choice;
  float* out;
};

__global__ __launch_bounds__(256) void tail_kernel_v14(TailArgs A) {
  __shared__ float a0[16][512];
  __shared__ float a1[16][512];
  const int tid = threadIdx.x, bid = blockIdx.x;

  for (int e = tid; e < 16 * 256; e += 256) {
    int r = e >> 8, jj = e & 255;
    a0[r][jj] = h2f(A.seq[((((size_t)bid * T_ + (T_ - 1)) * 16 + r) << 8) + jj]);
  }
  __syncthreads();

  dense<128, 256, true>(a0, a1, A.ef1w, A.ef1b, tid); __syncthreads();
  dense<64, 128, true>(a1, a0, A.ef2w, A.ef2b, tid);  __syncthreads();

  const float pi = *A.pi;
  for (int e = tid; e < 16 * 64; e += 256) {
    int r = e >> 6, n = e & 63;
    size_t rg = (size_t)bid * 16 + r;
    float m  = dotK<64>(a0[r], A.mean_w   + n * 64) + A.mean_b[n];
    float lv = dotK<64>(a0[r], A.logvar_w + n * 64) + A.logvar_b[n];
    float sc = __expf(dotK<64>(a0[r], A.scale_w + n * 64) + A.scale_b[n]);
    float sh = dotK<64>(a0[r], A.shape_w + n * 64) + A.shape_b[n];
    A.out[196608 + rg * 64 + n] = m;
    A.out[327680 + rg * 64 + n] = lv;
    A.out[458752 + rg * 64 + n] = sc;
    A.out[589824 + rg * 64 + n] = sh;
    float zg = m + A.eps[rg * 64 + n] * __expf(0.5f * lv);
    float L  = log1pf(-A.u[rg * 64 + n]);
    float zp = sc / sh * (__expf(-sh * L) - 1.f);
    a1[r][n] = (A.choice[rg] < pi) ? zg : zp;
  }
  __syncthreads();

  dense<128, 64, true>(a1, a0, A.df1w, A.df1b, tid);   __syncthreads();
  dense<500, 128, true>(a0, a1, A.df2w, A.df2b, tid);  __syncthreads();
  dense<96, 500, false>(a1, a0, A.outw, A.outb, tid);  __syncthreads();
  dense<96, 96, false>(a0, a1, A.finw, A.finb, tid);   __syncthreads();

  for (int e = tid; e < 16 * FUT_; e += 256) {
    int r = e / FUT_, n = e - r * FUT_;
    A.out[((size_t)bid * 16 + r) * FUT_ + n] = a1[r][n];
  }
}

// ---------------- launch ----------------
extern "C" void kernel_launch(void* const* d_in, const int* in_sizes, int n_in,
                              void* d_out, int out_size, void* d_ws, size_t ws_size,
                              hipStream_t stream) {
  (void)in_sizes; (void)n_in; (void)out_size; (void)ws_size;

  const float* X      = (const float*)d_in[0];
  const float* Wih0   = (const float*)d_in[1];
  const float* Wih    = (const float*)d_in[2];
  const float* Whh    = (const float*)d_in[3];
  const float* b      = (const float*)d_in[4];
  const float* ef1w   = (const float*)d_in[5];
  const float* ef1b   = (const float*)d_in[6];
  const float* ef2w   = (const float*)d_in[7];
  const float* ef2b   = (const float*)d_in[8];
  const float* mean_w = (const float*)d_in[9];
  const float* mean_b = (const float*)d_in[10];
  const float* logvar_w = (const float*)d_in[11];
  const float* logvar_b = (const float*)d_in[12];
  const float* scale_w  = (const float*)d_in[13];
  const float* scale_b  = (const float*)d_in[14];
  const float* shape_w  = (const float*)d_in[15];
  const float* shape_b  = (const float*)d_in[16];
  const float* df1w   = (const float*)d_in[17];
  const float* df1b   = (const float*)d_in[18];
  const float* df2w   = (const float*)d_in[19];
  const float* df2b   = (const float*)d_in[20];
  const float* outw   = (const float*)d_in[21];
  const float* outb   = (const float*)d_in[22];
  const float* finw   = (const float*)d_in[23];
  const float* finb   = (const float*)d_in[24];
  const float* pi_g   = (const float*)d_in[25];
  const float* eps    = (const float*)d_in[26];
  const float* u      = (const float*)d_in[27];
  const float* choice = (const float*)d_in[28];

  float* out = (float*)d_out;
  u16* wfh = (u16*)((char*)d_ws + WFH_OFF);
  u16* wfx = (u16*)((char*)d_ws + WFX_OFF);
  u16* seq = (u16*)((char*)d_ws + SEQ2_OFF);

  pack_weights_v14<<<2560, 256, 0, stream>>>(Wih0, Wih, Whh, wfh, wfx);

  lstm_layer_v14<true><<<NBLK, 1024, 0, stream>>>(X, seq, wfx, wfh, b);
  for (int l = 1; l < NL_; ++l)
    lstm_layer_v14<false><<<NBLK, 1024, 0, stream>>>(nullptr, seq,
        wfx + (size_t)l * WFL9, wfh + (size_t)l * WFL9, b + l * 1024);

  TailArgs A;
  A.seq = seq;
  A.ef1w = ef1w; A.ef1b = ef1b; A.ef2w = ef2w; A.ef2b = ef2b;
  A.mean_w = mean_w; A.mean_b = mean_b; A.logvar_w = logvar_w; A.logvar_b = logvar_b;
  A.scale_w = scale_w; A.scale_b = scale_b; A.shape_w = shape_w; A.shape_b = shape_b;
  A.df1w = df1w; A.df1b = df1b; A.df2w = df2w; A.df2b = df2b;
  A.outw = outw; A.outb = outb; A.finw = finw; A.finb = finb;
  A.pi = pi_g; A.eps = eps; A.u = u; A.choice = choice;
  A.out = out;
  tail_kernel_v14<<<NBLK, 256, 0, stream>>>(A);
}